// Round 1
// baseline (77.722 us; speedup 1.0000x reference)
//
#include <hip/hip_runtime.h>

// x: (32, 3, 1024, 1024) f32, l: (32,2) i32
// out = [ full: 32*3*1024*1024 f32 , patch: 32*3*128*128 f32 ]
//
// rows = l0 - 193 + i (i in [0,128)), cols = l1 - 193 + j (j in [0,128))
// patch[b,c,i,j] = valid ? x[b,c,row,col] : 0
// full = x masked to the valid window, 0 elsewhere.

#define FULL_ELEMS (32L * 3 * 1024 * 1024)   // 100663296
#define PATCH_ELEMS (32L * 3 * 128 * 128)    // 1572864

__global__ __launch_bounds__(256) void full_fill(const float* __restrict__ x,
                                                 const int* __restrict__ l,
                                                 float* __restrict__ full) {
    long tid = (long)blockIdx.x * 256 + threadIdx.x;   // one float4 per thread
    int w4 = (int)(tid & 255);            // float4 index along W (W/4 = 256)
    int r  = (int)((tid >> 8) & 1023);
    int b  = (int)(tid / (256L * 1024 * 3));
    int l0 = l[2 * b];
    int l1 = l[2 * b + 1];
    int i = r - (l0 - 193);               // patch row index
    float4 out = make_float4(0.f, 0.f, 0.f, 0.f);
    if ((unsigned)i < 128u) {
        int w0 = w4 * 4;
        int jbase = w0 - (l1 - 193);      // patch col index of element k=0
        if (jbase >= -3 && jbase < 128) { // any of 4 elems inside col window
            const float4 xin = *(const float4*)(x + tid * 4);
            float v[4] = {xin.x, xin.y, xin.z, xin.w};
            float o[4];
#pragma unroll
            for (int k = 0; k < 4; ++k) {
                int j = jbase + k;
                o[k] = ((unsigned)j < 128u) ? v[k] : 0.f;
            }
            out = make_float4(o[0], o[1], o[2], o[3]);
        }
    }
    *(float4*)(full + tid * 4) = out;
}

__global__ __launch_bounds__(256) void patch_fill(const float* __restrict__ x,
                                                  const int* __restrict__ l,
                                                  float* __restrict__ patch) {
    int tid = blockIdx.x * 256 + threadIdx.x;  // one float4 (4 j's) per thread
    int j4 = tid & 31;                   // 128/4 = 32
    int i  = (tid >> 5) & 127;
    int c  = (tid >> 12) % 3;            // 32*128 = 4096
    int b  = tid / (32 * 128 * 3);
    int l0 = l[2 * b];
    int l1 = l[2 * b + 1];
    int r = l0 - 193 + i;
    float o[4] = {0.f, 0.f, 0.f, 0.f};
    if ((unsigned)r < 1024u) {
        const float* xrow = x + (((long)(b * 3 + c) * 1024 + r) << 10);
#pragma unroll
        for (int k = 0; k < 4; ++k) {
            int w = l1 - 193 + j4 * 4 + k;
            if ((unsigned)w < 1024u) o[k] = xrow[w];
        }
    }
    *(float4*)(patch + (long)tid * 4) = make_float4(o[0], o[1], o[2], o[3]);
}

extern "C" void kernel_launch(void* const* d_in, const int* in_sizes, int n_in,
                              void* d_out, int out_size, void* d_ws, size_t ws_size,
                              hipStream_t stream) {
    const float* x = (const float*)d_in[0];
    const int*   l = (const int*)d_in[1];
    float* full  = (float*)d_out;
    float* patch = full + FULL_ELEMS;

    // full: 100663296 / 4 elems per thread = 25165824 threads / 256 = 98304 blocks
    full_fill<<<98304, 256, 0, stream>>>(x, l, full);
    // patch: 1572864 / 4 = 393216 threads / 256 = 1536 blocks
    patch_fill<<<1536, 256, 0, stream>>>(x, l, patch);
}